// Round 5
// baseline (319.193 us; speedup 1.0000x reference)
//
#include <hip/hip_runtime.h>

typedef __attribute__((ext_vector_type(8))) short bf16x8;
typedef __attribute__((ext_vector_type(4))) float floatx4;

constexpr int BATCH = 4;
constexpr int SEQ   = 2048;
constexpr int DIMN  = 1024;
constexpr int M1    = BATCH * SEQ; // 8192

__device__ __forceinline__ short f2bf(float f) {
    union { float f; unsigned u; } x; x.f = f;
    unsigned r = x.u + 0x7fffu + ((x.u >> 16) & 1u); // RNE
    return (short)(r >> 16);
}
__device__ __forceinline__ float bf2f(short s) {
    union { unsigned u; float f; } x; x.u = ((unsigned)(unsigned short)s) << 16;
    return x.f;
}

__device__ __forceinline__ void async16(const void* g, void* l) {
    __builtin_amdgcn_global_load_lds(
        (const __attribute__((address_space(1))) unsigned int*)g,
        (__attribute__((address_space(3))) unsigned int*)l, 16, 0, 0);
}

#define WAITVM(N) asm volatile("s_waitcnt vmcnt(" #N ")" ::: "memory")
#define MEMFENCE  asm volatile("" ::: "memory")
#define BAR()     __builtin_amdgcn_s_barrier()
#define PRIO(x)   __builtin_amdgcn_s_setprio(x)

// ===========================================================================
// gemm97: m97-style high-occupancy core. 128x128 tile, BK=32, 4 waves (2x2,
// per-wave 64x64), dbuf LDS 2x16KB = 32KB -> ~4 blocks/CU (16 waves/CU).
// Single barrier per K-tile; drain-0 vmcnt hidden by cross-block TLP
// (m97 mechanism: 912 TF with this schedule at >=3 blocks/CU).
// Swizzle for 64B rows: byte ^= ((row&6)<<3)  (2-way max on ds_read_b128),
// applied on pre-swizzled global source (global_load_lds writes linearly)
// and on the read address.
// ===========================================================================
template<bool OUT_BF16>
__device__ __forceinline__ void gemm97(
    const short* __restrict__ Ab, int lda,
    const short* __restrict__ Bb, int ldb,
    void* __restrict__ Cb, int ldc,
    const float* __restrict__ bias, int K, float scale,
    int m0, int n0)
{
    constexpr int ABY  = 8192;        // A: 128 rows x 64B
    constexpr int BUFB = 16384;       // + B: 128 rows x 64B
    __shared__ alignas(16) char smem[2 * BUFB];   // 32 KB
    char* lds = smem;

    const int t    = threadIdx.x;   // 0..255
    const int lane = t & 63;
    const int wave = t >> 6;        // 0..3
    const int wr   = wave >> 1;     // 0..1
    const int wc   = wave & 1;      // 0..1
    const int lr   = lane & 15;
    const int lq   = lane >> 4;

    // staging: op covers 64 rows (256 thr x 16B = 4KB); thread row = t>>2,
    // phys col byte = (t&3)*16; logical col = phys ^ ((row&6)<<3).
    const int srow  = t >> 2;                       // 0..63
    const int scolb = ((t & 3) * 16) ^ ((srow & 6) << 3);
    const short* pa = Ab + (size_t)(m0 + srow) * lda + (scolb >> 1);
    const short* pb = Bb + (size_t)(n0 + srow) * ldb + (scolb >> 1);
    const size_t rsa = (size_t)64 * lda;
    const size_t rsb = (size_t)64 * ldb;
    const int ldst = t * 16;

    // read: row = base + lr (base mult of 16) -> (row>>1)&3 = (lr>>1)&3
    const int cp  = ((lq ^ ((lr >> 1) & 3)) << 4);
    const int roA = (wr * 64 + lr) * 64;            // + m*1024
    const int roB = ABY + (wc * 64 + lr) * 64;      // + n*1024

    floatx4 acc[4][4];
    #pragma unroll
    for (int m = 0; m < 4; ++m)
        #pragma unroll
        for (int n = 0; n < 4; ++n) acc[m][n] = (floatx4)(0.f);

    auto stage = [&](int d, int kt) {
        const short* qa = pa + kt * 32;   // K-tile = 32 shorts = 64B
        const short* qb = pb + kt * 32;
        async16(qa,       lds + d +        ldst);
        async16(qa + rsa, lds + d + 4096 + ldst);
        async16(qb,       lds + d + ABY +        ldst);
        async16(qb + rsb, lds + d + ABY + 4096 + ldst);
    };

    const int NT = K >> 5;

    stage(0, 0);
    WAITVM(0);
    BAR(); MEMFENCE;

    for (int tt = 0; tt < NT; ++tt) {
        const char* rb = lds + (tt & 1) * BUFB;
        bf16x8 a[4], b[4];
        #pragma unroll
        for (int m = 0; m < 4; ++m) a[m] = *(const bf16x8*)(rb + roA + m * 1024 + cp);
        #pragma unroll
        for (int n = 0; n < 4; ++n) b[n] = *(const bf16x8*)(rb + roB + n * 1024 + cp);
        if (tt + 1 < NT) stage(((tt + 1) & 1) * BUFB, tt + 1);
        PRIO(1);
        #pragma unroll
        for (int m = 0; m < 4; ++m)
            #pragma unroll
            for (int n = 0; n < 4; ++n)
                acc[m][n] = __builtin_amdgcn_mfma_f32_16x16x32_bf16(a[m], b[n], acc[m][n], 0, 0, 0);
        PRIO(0); MEMFENCE;
        if (tt + 1 < NT) WAITVM(0);
        BAR(); MEMFENCE;
    }

    // D layout: col = lane&15, row = (lane>>4)*4 + r
    #pragma unroll
    for (int n = 0; n < 4; ++n) {
        const int gn = n0 + wc * 64 + n * 16 + lr;
        const float bv = bias ? bias[gn] : 0.f;
        #pragma unroll
        for (int m = 0; m < 4; ++m) {
            #pragma unroll
            for (int r = 0; r < 4; ++r) {
                const int gm = m0 + wr * 64 + m * 16 + lq * 4 + r;
                const float v = acc[m][n][r] * scale + bv;
                if (OUT_BF16) ((short*)Cb)[(size_t)gm * ldc + gn] = f2bf(v);
                else          ((float*)Cb)[(size_t)gm * ldc + gn] = v;
            }
        }
    }
}

// ===========================================================================
// gemm256 (scores): unchanged round-4 counted 4-phase core.
// ===========================================================================
template<bool OUT_BF16>
__device__ __forceinline__ void gemm256(
    const short* __restrict__ Ab, int lda,
    const short* __restrict__ Bb, int ldb,
    void* __restrict__ Cb, int ldc,
    const float* __restrict__ bias, int K, float scale,
    int m0, int n0)
{
    constexpr int ABY  = 32768;
    constexpr int BUFB = 65536;
    __shared__ alignas(16) char smem[2 * BUFB];   // 128 KB
    char* lds = smem;

    const int t    = threadIdx.x;   // 0..511
    const int lane = t & 63;
    const int wave = t >> 6;
    const int wr   = wave >> 2;     // 0..1
    const int wc   = wave & 3;      // 0..3
    const int lr   = lane & 15;
    const int lq   = lane >> 4;

    const int srow  = t >> 3;
    const int scol  = (((t & 7) * 16) ^ ((srow & 7) << 4)) >> 1;
    const short* pa0 = Ab + (size_t)(m0 + srow) * lda + scol;
    const short* pb0 = Bb + (size_t)(n0 + srow) * ldb + scol;
    const size_t rsa = (size_t)64 * lda;
    const size_t rsb = (size_t)64 * ldb;
    const int ldst = t * 16;

    const int roA = (wr * 128 + lr) * 128;           // + m*2048
    const int roB = ABY + (wc * 64 + lr) * 128;      // + n*2048
    const int cs  = (lane & 7) << 4;
    const int cp0 = (lq << 4) ^ cs;
    const int cp1 = (64 | (lq << 4)) ^ cs;

    floatx4 acc[8][4];
    #pragma unroll
    for (int m = 0; m < 8; ++m)
        #pragma unroll
        for (int n = 0; n < 4; ++n) acc[m][n] = (floatx4)(0.f);

    auto stB01 = [&](int d, int kt) { const short* p = pb0 + kt * 64;
        async16(p,       lds + d + ABY +        ldst);
        async16(p + rsb, lds + d + ABY + 8192 + ldst); };
    auto stB23 = [&](int d, int kt) { const short* p = pb0 + kt * 64;
        async16(p + 2 * rsb, lds + d + ABY + 16384 + ldst);
        async16(p + 3 * rsb, lds + d + ABY + 24576 + ldst); };
    auto stA02 = [&](int d, int kt) { const short* p = pa0 + kt * 64;
        async16(p,           lds + d +         ldst);
        async16(p + 2 * rsa, lds + d + 16384 + ldst); };
    auto stA13 = [&](int d, int kt) { const short* p = pa0 + kt * 64;
        async16(p + rsa,     lds + d +  8192 + ldst);
        async16(p + 3 * rsa, lds + d + 24576 + ldst); };

    const int NT = K >> 6;

    stB01(0, 0); stB23(0, 0); stA02(0, 0); stA13(0, 0);
    if (NT > 1) { stB01(BUFB, 1); WAITVM(2); }
    else        { WAITVM(0); }
    BAR(); MEMFENCE;

    int bu = 0;
    for (int tt = 0; tt < NT; ++tt) {
        const int ob = bu ^ BUFB;
        const char* rb = lds + bu;
        bf16x8 a0[4], a1[4], bf4[4];

        // P0
        #pragma unroll
        for (int m = 0; m < 4; ++m) a0[m]  = *(const bf16x8*)(rb + roA + m * 2048 + cp0);
        #pragma unroll
        for (int n = 0; n < 4; ++n) bf4[n] = *(const bf16x8*)(rb + roB + n * 2048 + cp0);
        if (tt + 1 < NT) stB23(ob, tt + 1);
        BAR(); MEMFENCE;
        PRIO(1);
        #pragma unroll
        for (int m = 0; m < 4; ++m)
            #pragma unroll
            for (int n = 0; n < 4; ++n)
                acc[m][n] = __builtin_amdgcn_mfma_f32_16x16x32_bf16(a0[m], bf4[n], acc[m][n], 0, 0, 0);
        PRIO(0); MEMFENCE;
        if (tt + 1 < NT) { WAITVM(4); } else { WAITVM(0); }
        BAR(); MEMFENCE;

        // P1
        #pragma unroll
        for (int m = 0; m < 4; ++m) a1[m] = *(const bf16x8*)(rb + roA + (m + 4) * 2048 + cp0);
        if (tt + 1 < NT) stA02(ob, tt + 1);
        BAR(); MEMFENCE;
        PRIO(1);
        #pragma unroll
        for (int m = 0; m < 4; ++m)
            #pragma unroll
            for (int n = 0; n < 4; ++n)
                acc[m + 4][n] = __builtin_amdgcn_mfma_f32_16x16x32_bf16(a1[m], bf4[n], acc[m + 4][n], 0, 0, 0);
        PRIO(0); MEMFENCE;
        BAR(); MEMFENCE;

        // P2
        #pragma unroll
        for (int m = 0; m < 4; ++m) a0[m]  = *(const bf16x8*)(rb + roA + m * 2048 + cp1);
        #pragma unroll
        for (int n = 0; n < 4; ++n) bf4[n] = *(const bf16x8*)(rb + roB + n * 2048 + cp1);
        if (tt + 1 < NT) stA13(ob, tt + 1);
        BAR(); MEMFENCE;
        PRIO(1);
        #pragma unroll
        for (int m = 0; m < 4; ++m)
            #pragma unroll
            for (int n = 0; n < 4; ++n)
                acc[m][n] = __builtin_amdgcn_mfma_f32_16x16x32_bf16(a0[m], bf4[n], acc[m][n], 0, 0, 0);
        PRIO(0); MEMFENCE;
        BAR(); MEMFENCE;

        // P3
        #pragma unroll
        for (int m = 0; m < 4; ++m) a1[m] = *(const bf16x8*)(rb + roA + (m + 4) * 2048 + cp1);
        if (tt + 2 < NT) stB01(bu, tt + 2);
        BAR(); MEMFENCE;
        PRIO(1);
        #pragma unroll
        for (int m = 0; m < 4; ++m)
            #pragma unroll
            for (int n = 0; n < 4; ++n)
                acc[m + 4][n] = __builtin_amdgcn_mfma_f32_16x16x32_bf16(a1[m], bf4[n], acc[m + 4][n], 0, 0, 0);
        PRIO(0); MEMFENCE;
        if (tt + 1 < NT) {
            if (tt + 2 < NT) { WAITVM(4); } else { WAITVM(2); }
        }
        BAR(); MEMFENCE;
        bu = ob;
    }

    #pragma unroll
    for (int n = 0; n < 4; ++n) {
        const int gn = n0 + wc * 64 + n * 16 + lr;
        const float bv = bias ? bias[gn] : 0.f;
        #pragma unroll
        for (int m = 0; m < 8; ++m) {
            #pragma unroll
            for (int r = 0; r < 4; ++r) {
                const int gm = m0 + wr * 128 + m * 16 + lq * 4 + r;
                const float v = acc[m][n][r] * scale + bv;
                if (OUT_BF16) ((short*)Cb)[(size_t)gm * ldc + gn] = f2bf(v);
                else          ((float*)Cb)[(size_t)gm * ldc + gn] = v;
            }
        }
    }
}

// ===========================================================================
// gemm128 (pv): unchanged round-4 counted triple-buffer core.
// ===========================================================================
template<bool OUT_BF16>
__device__ __forceinline__ void gemm128(
    const short* __restrict__ Ab, int lda,
    const short* __restrict__ Bb, int ldb,
    void* __restrict__ Cb, int ldc,
    const float* __restrict__ bias, int K, float scale,
    int m0, int n0)
{
    constexpr int ABY  = 16384;
    constexpr int BUFB = ABY + 32768;  // 48KB
    __shared__ alignas(16) char smem[3 * BUFB];
    char* lds = smem;

    const int t    = threadIdx.x;
    const int lane = t & 63;
    const int wave = t >> 6;
    const int wr   = wave >> 2;
    const int wc   = wave & 3;
    const int lr   = lane & 15;
    const int lq   = lane >> 4;

    const int srow  = t >> 3;
    const int scol  = (((t & 7) * 16) ^ ((srow & 7) << 4)) >> 1;
    const short* pa0 = Ab + (size_t)(m0 + srow) * lda + scol;
    const short* pb0 = Bb + (size_t)(n0 + srow) * ldb + scol;
    const size_t rsa = (size_t)64 * lda;
    const size_t rsb = (size_t)64 * ldb;
    const int ldst = t * 16;

    const int roA = (wr * 64 + lr) * 128;
    const int roB = ABY + (wc * 64 + lr) * 128;
    const int cs  = (lane & 7) << 4;
    const int cp0 = (lq << 4) ^ cs;
    const int cp1 = (64 | (lq << 4)) ^ cs;

    floatx4 acc[4][4];
    #pragma unroll
    for (int m = 0; m < 4; ++m)
        #pragma unroll
        for (int n = 0; n < 4; ++n) acc[m][n] = (floatx4)(0.f);

    auto stA = [&](int d, int kt) { const short* p = pa0 + kt * 64;
        async16(p,       lds + d +        ldst);
        async16(p + rsa, lds + d + 8192 + ldst); };
    auto stB01 = [&](int d, int kt) { const short* p = pb0 + kt * 64;
        async16(p,       lds + d + ABY +        ldst);
        async16(p + rsb, lds + d + ABY + 8192 + ldst); };
    auto stB23 = [&](int d, int kt) { const short* p = pb0 + kt * 64;
        async16(p + 2 * rsb, lds + d + ABY + 16384 + ldst);
        async16(p + 3 * rsb, lds + d + ABY + 24576 + ldst); };

    const int NT = K >> 6;

    stA(0, 0); stB01(0, 0); stB23(0, 0);
    if (NT > 1) { stA(BUFB, 1); stB01(BUFB, 1); stB23(BUFB, 1); WAITVM(6); }
    else        { WAITVM(0); }
    BAR(); MEMFENCE;

    int cb = 0;
    for (int tt = 0; tt < NT; ++tt) {
        const char* rb = lds + cb;
        int sb = cb + 2 * BUFB; if (sb >= 3 * BUFB) sb -= 3 * BUFB;
        bf16x8 a[4], b[4];

        // P0 (k0); stage A + B01 of t+2
        #pragma unroll
        for (int m = 0; m < 4; ++m) a[m] = *(const bf16x8*)(rb + roA + m * 2048 + cp0);
        #pragma unroll
        for (int n = 0; n < 4; ++n) b[n] = *(const bf16x8*)(rb + roB + n * 2048 + cp0);
        if (tt + 2 < NT) { stA(sb, tt + 2); stB01(sb, tt + 2); }
        BAR(); MEMFENCE;
        PRIO(1);
        #pragma unroll
        for (int m = 0; m < 4; ++m)
            #pragma unroll
            for (int n = 0; n < 4; ++n)
                acc[m][n] = __builtin_amdgcn_mfma_f32_16x16x32_bf16(a[m], b[n], acc[m][n], 0, 0, 0);
        PRIO(0); MEMFENCE;
        BAR(); MEMFENCE;

        // P1 (k1); stage B23 of t+2; certify tile t+1
        #pragma unroll
        for (int m = 0; m < 4; ++m) a[m] = *(const bf16x8*)(rb + roA + m * 2048 + cp1);
        #pragma unroll
        for (int n = 0; n < 4; ++n) b[n] = *(const bf16x8*)(rb + roB + n * 2048 + cp1);
        if (tt + 2 < NT) stB23(sb, tt + 2);
        BAR(); MEMFENCE;
        PRIO(1);
        #pragma unroll
        for (int m = 0; m < 4; ++m)
            #pragma unroll
            for (int n = 0; n < 4; ++n)
                acc[m][n] = __builtin_amdgcn_mfma_f32_16x16x32_bf16(a[m], b[n], acc[m][n], 0, 0, 0);
        PRIO(0); MEMFENCE;
        if (tt + 1 < NT) {
            if (tt + 2 < NT) { WAITVM(6); } else { WAITVM(0); }
        }
        BAR(); MEMFENCE;
        cb += BUFB; if (cb >= 3 * BUFB) cb = 0;
    }

    #pragma unroll
    for (int n = 0; n < 4; ++n) {
        const int gn = n0 + wc * 64 + n * 16 + lr;
        const float bv = bias ? bias[gn] : 0.f;
        #pragma unroll
        for (int m = 0; m < 4; ++m) {
            #pragma unroll
            for (int r = 0; r < 4; ++r) {
                const int gm = m0 + wr * 64 + m * 16 + lq * 4 + r;
                const float v = acc[m][n][r] * scale + bv;
                if (OUT_BF16) ((short*)Cb)[(size_t)gm * ldc + gn] = f2bf(v);
                else          ((float*)Cb)[(size_t)gm * ldc + gn] = v;
            }
        }
    }
}

// ---------------------------------------------------------------------------
// proj: gemm97 128x128. 1536 blocks = 3 mats x 64 m x 8 n, XCD-swizzled.
// 4 blocks/CU -> 6 blocks/CU of backfilled work, no ragged round.
// ---------------------------------------------------------------------------
__global__ __launch_bounds__(256, 4)
void proj_qkv(const short* __restrict__ xq, const short* __restrict__ xk,
              const short* __restrict__ xv,
              const short* __restrict__ Wq_, const short* __restrict__ Wk_,
              const short* __restrict__ Wv_,
              const float* __restrict__ bq_, const float* __restrict__ bk_,
              const float* __restrict__ bv_,
              short* __restrict__ q, short* __restrict__ k, short* __restrict__ vp)
{
    const int b   = blockIdx.x;
    const int xcd = b & 7;
    const int i   = b >> 3;          // 0..191
    const int z   = i >> 6;          // 0..2 (q,k,v)
    const int r   = i & 63;
    const int mm  = r >> 3;          // 0..7
    const int nn  = r & 7;           // 0..7
    const short* X = (z == 0) ? xq : (z == 1) ? xk : xv;
    const short* W = (z == 0) ? Wq_ : (z == 1) ? Wk_ : Wv_;
    const float* bb = (z == 0) ? bq_ : (z == 1) ? bk_ : bv_;
    short* O = (z == 0) ? q : (z == 1) ? k : vp;
    gemm97<true>(X, DIMN, W, DIMN, (void*)O, DIMN, bb, DIMN, 1.f,
                 (xcd * 8 + mm) * 128, nn * 128);
}

// scores: 256 blocks, 256x256, 4-phase counted core (unchanged).
__global__ __launch_bounds__(512, 2)
void gemm_scores(const short* __restrict__ q, const short* __restrict__ k,
                 short* __restrict__ S, float scale)
{
    const int b   = blockIdx.x;
    const int xcd = b & 7;
    const int i   = b >> 3;          // 0..31
    const int bz  = xcd >> 1;
    const int mh  = xcd & 1;
    const int mm  = i >> 3;          // 0..3
    const int nn  = i & 7;           // 0..7
    gemm256<true>(q + (size_t)bz * SEQ * DIMN, DIMN,
                  k + (size_t)bz * SEQ * DIMN, DIMN,
                  (void*)(S + (size_t)bz * SEQ * SEQ), SEQ,
                  nullptr, DIMN, scale,
                  (mh * 4 + mm) * 256, nn * 256);
}

// PV: 256 blocks, 128x256, K=2048 (unchanged).
__global__ __launch_bounds__(512, 2)
void gemm_pv(const short* __restrict__ P, const short* __restrict__ vt,
             float* __restrict__ O)
{
    const int b   = blockIdx.x;
    const int xcd = b & 7;
    const int i   = b >> 3;          // 0..31
    const int bz  = xcd >> 1;
    const int mh  = xcd & 1;
    const int mm  = i >> 2;          // 0..7
    const int nn  = i & 3;           // 0..3
    gemm128<false>(P  + (size_t)bz * SEQ * SEQ,  SEQ,
                   vt + (size_t)bz * DIMN * SEQ, SEQ,
                   (void*)(O + (size_t)bz * SEQ * DIMN), DIMN,
                   nullptr, SEQ, 1.f,
                   (mh * 8 + mm) * 128, nn * 256);
}

// ---------------------------------------------------------------------------
// fp32 -> bf16 bulk convert, 6 arrays in one launch (z picks; z<3 weights).
// ---------------------------------------------------------------------------
__global__ __launch_bounds__(256)
void cvt6(const float* __restrict__ w0, short* __restrict__ ow0,
          const float* __restrict__ w1, short* __restrict__ ow1,
          const float* __restrict__ w2, short* __restrict__ ow2,
          const float* __restrict__ x0, short* __restrict__ ox0,
          const float* __restrict__ x1, short* __restrict__ ox1,
          const float* __restrict__ x2, short* __restrict__ ox2,
          int n8w, int n8x)
{
    const int z = blockIdx.z;
    const float* in; short* out; int n8;
    switch (z) {
        case 0: in = w0; out = ow0; n8 = n8w; break;
        case 1: in = w1; out = ow1; n8 = n8w; break;
        case 2: in = w2; out = ow2; n8 = n8w; break;
        case 3: in = x0; out = ox0; n8 = n8x; break;
        case 4: in = x1; out = ox1; n8 = n8x; break;
        default: in = x2; out = ox2; n8 = n8x; break;
    }
    const int i = blockIdx.x * 256 + threadIdx.x;
    if (i >= n8) return;
    const float4 a0 = ((const float4*)in)[(size_t)i * 2];
    const float4 a1 = ((const float4*)in)[(size_t)i * 2 + 1];
    const float v[8] = {a0.x, a0.y, a0.z, a0.w, a1.x, a1.y, a1.z, a1.w};
    bf16x8 o;
    #pragma unroll
    for (int j = 0; j < 8; ++j) o[j] = f2bf(v[j]);
    *(bf16x8*)(out + (size_t)i * 8) = o;
}

// ---------------------------------------------------------------------------
// Effective biases: out[n] = b[n] + dot(ctx, W[n,:]) (ctx only for q,k).
// ---------------------------------------------------------------------------
__global__ __launch_bounds__(256)
void bias3(const float* __restrict__ Wq, const float* __restrict__ Wk,
           const float* __restrict__ Wv,
           const float* __restrict__ bq, const float* __restrict__ bk,
           const float* __restrict__ bv,
           const float* __restrict__ ctx,
           float* __restrict__ oq, float* __restrict__ ok, float* __restrict__ ov)
{
    const int z = blockIdx.y;
    const float* W = (z == 0) ? Wq : (z == 1) ? Wk : Wv;
    const float* b = (z == 0) ? bq : (z == 1) ? bk : bv;
    float*       o = (z == 0) ? oq : (z == 1) ? ok : ov;
    const int n    = blockIdx.x * 4 + (threadIdx.x >> 6);
    const int lane = threadIdx.x & 63;
    float s = 0.f;
    if (z < 2) {
        const float* row = W + (size_t)n * DIMN;
        for (int k = lane * 4; k < DIMN; k += 256) {
            const float4 x = *(const float4*)(row + k);
            const float4 c = *(const float4*)(ctx + k);
            s += x.x * c.x + x.y * c.y + x.z * c.z + x.w * c.w;
        }
        #pragma unroll
        for (int off = 32; off > 0; off >>= 1) s += __shfl_xor(s, off);
    }
    if (lane == 0) o[n] = b[n] + s;
}

// ---------------------------------------------------------------------------
// bf16 transpose: in [B][S][D] -> out [B][D][S], 64x64 LDS tiles.
// ---------------------------------------------------------------------------
__global__ __launch_bounds__(256)
void transpose_v(const short* __restrict__ in, short* __restrict__ out)
{
    __shared__ short t[64][68];
    const int b  = blockIdx.z;
    const int d0 = blockIdx.x * 64;
    const int s0 = blockIdx.y * 64;
    const int r  = threadIdx.x >> 3;
    const int c  = (threadIdx.x & 7) * 8;
    #pragma unroll
    for (int h = 0; h < 2; ++h) {
        const int s = r + h * 32;
        bf16x8 v = *(const bf16x8*)(in + ((size_t)b * SEQ + s0 + s) * DIMN + d0 + c);
        #pragma unroll
        for (int j = 0; j < 8; ++j) t[c + j][s] = v[j];
    }
    __syncthreads();
    #pragma unroll
    for (int h = 0; h < 2; ++h) {
        const int d = r + h * 32;
        bf16x8 v;
        #pragma unroll
        for (int j = 0; j < 8; ++j) v[j] = t[d][c + j];
        *(bf16x8*)(out + ((size_t)b * DIMN + d0 + d) * SEQ + s0 + c) = v;
    }
}

// ---------------------------------------------------------------------------
// Row softmax, in place on bf16 [M1 rows][SEQ].
// ---------------------------------------------------------------------------
__global__ __launch_bounds__(256)
void softmax_kernel(short* __restrict__ P)
{
    const int bid = blockIdx.x;
    const int xcd = bid & 7;
    const int i   = bid >> 3;            // 0..1023
    const int row = (xcd >> 1) * SEQ + (xcd & 1) * 1024 + i;
    short* p = P + (size_t)row * SEQ;
    const int t    = threadIdx.x;
    const int lane = t & 63;
    const int wave = t >> 6;
    __shared__ float red[8];

    bf16x8 raw = *(const bf16x8*)(p + t * 8);
    float v[8];
    float mx = -1e30f;
    #pragma unroll
    for (int j = 0; j < 8; ++j) { v[j] = bf2f(raw[j]); mx = fmaxf(mx, v[j]); }
    #pragma unroll
    for (int off = 32; off > 0; off >>= 1) mx = fmaxf(mx, __shfl_xor(mx, off));
    if (lane == 0) red[wave] = mx;
    __syncthreads();
    mx = fmaxf(fmaxf(red[0], red[1]), fmaxf(red[2], red[3]));

    float e[8], s = 0.f;
    #pragma unroll
    for (int j = 0; j < 8; ++j) { e[j] = __expf(v[j] - mx); s += e[j]; }
    #pragma unroll
    for (int off = 32; off > 0; off >>= 1) s += __shfl_xor(s, off);
    if (lane == 0) red[4 + wave] = s;
    __syncthreads();
    s = red[4] + red[5] + red[6] + red[7];
    const float inv = 1.f / s;

    bf16x8 o;
    #pragma unroll
    for (int j = 0; j < 8; ++j) o[j] = f2bf(e[j] * inv);
    *(bf16x8*)(p + t * 8) = o;
}

// ---------------------------------------------------------------------------
extern "C" void kernel_launch(void* const* d_in, const int* in_sizes, int n_in,
                              void* d_out, int out_size, void* d_ws, size_t ws_size,
                              hipStream_t stream)
{
    const float* query = (const float*)d_in[0];
    const float* key_  = (const float*)d_in[1];
    const float* value = (const float*)d_in[2];
    const float* ctx   = (const float*)d_in[3];
    const float* Wq    = (const float*)d_in[4];
    const float* bq    = (const float*)d_in[5];
    const float* Wk    = (const float*)d_in[6];
    const float* bk    = (const float*)d_in[7];
    const float* Wv    = (const float*)d_in[8];
    const float* bv    = (const float*)d_in[9];

    // Workspace (80 MB) + d_out (32 MB) doubling as scratch for xv/vp:
    //   ws:  xq [0,16) xk [16,32)  -> dead after proj -> S_b [0,32)
    //        q_b [32,48) k_b [48,64)
    //        W3 [64,70) + biases    -> dead after proj -> v_t [64,80)
    //   d_out: xv [0,16) vp [16,32) -> dead after transpose -> final output
    char* ws = (char*)d_ws;
    char* od = (char*)d_out;
    const size_t MB = 1ull << 20;
    short* xq   = (short*)(ws);
    short* xk   = (short*)(ws + 16 * MB);
    short* q_b  = (short*)(ws + 32 * MB);
    short* k_b  = (short*)(ws + 48 * MB);
    short* Wq_b = (short*)(ws + 64 * MB);
    short* Wk_b = (short*)(ws + 66 * MB);
    short* Wv_b = (short*)(ws + 68 * MB);
    float* bq_e = (float*)(ws + 70 * MB);
    float* bk_e = (float*)(ws + 70 * MB + 4096);
    float* bv_e = (float*)(ws + 70 * MB + 8192);
    short* S_b  = (short*)(ws);
    short* v_t  = (short*)(ws + 64 * MB);
    short* xv   = (short*)(od);
    short* vp   = (short*)(od + 16 * MB);

    dim3 blk(256);
    dim3 blk512(512);
    const int W8 = DIMN * DIMN / 8;  // 131072
    const int X8 = M1 * DIMN / 8;    // 1048576

    cvt6<<<dim3(X8 / 256, 1, 6), blk, 0, stream>>>(Wq, Wq_b, Wk, Wk_b, Wv, Wv_b,
                                                   query, xq, key_, xk, value, xv,
                                                   W8, X8);
    bias3<<<dim3(DIMN / 4, 3), blk, 0, stream>>>(Wq, Wk, Wv, bq, bk, bv, ctx,
                                                 bq_e, bk_e, bv_e);

    proj_qkv<<<dim3(1536), blk, 0, stream>>>(xq, xk, xv, Wq_b, Wk_b, Wv_b,
                                             bq_e, bk_e, bv_e, q_b, k_b, vp);
    transpose_v<<<dim3(DIMN / 64, SEQ / 64, BATCH), blk, 0, stream>>>(vp, v_t);

    const float scale = 1.0f / 32.0f; // DIMN^-0.5
    gemm_scores<<<dim3(256), blk512, 0, stream>>>(q_b, k_b, S_b, scale);

    softmax_kernel<<<dim3(M1), blk, 0, stream>>>(S_b);

    gemm_pv<<<dim3(256), blk512, 0, stream>>>(S_b, v_t, (float*)d_out);
}

// Round 6
// 302.396 us; speedup vs baseline: 1.0555x; 1.0555x over previous
//
#include <hip/hip_runtime.h>

typedef __attribute__((ext_vector_type(8))) short bf16x8;
typedef __attribute__((ext_vector_type(4))) float floatx4;

constexpr int BATCH = 4;
constexpr int SEQ   = 2048;
constexpr int DIMN  = 1024;
constexpr int M1    = BATCH * SEQ; // 8192

__device__ __forceinline__ short f2bf(float f) {
    union { float f; unsigned u; } x; x.f = f;
    unsigned r = x.u + 0x7fffu + ((x.u >> 16) & 1u); // RNE
    return (short)(r >> 16);
}
__device__ __forceinline__ float bf2f(short s) {
    union { unsigned u; float f; } x; x.u = ((unsigned)(unsigned short)s) << 16;
    return x.f;
}

__device__ __forceinline__ void async16(const void* g, void* l) {
    __builtin_amdgcn_global_load_lds(
        (const __attribute__((address_space(1))) unsigned int*)g,
        (__attribute__((address_space(3))) unsigned int*)l, 16, 0, 0);
}

#define WAITVM(N) asm volatile("s_waitcnt vmcnt(" #N ")" ::: "memory")
#define MEMFENCE  asm volatile("" ::: "memory")
#define BAR()     __builtin_amdgcn_s_barrier()
#define PRIO(x)   __builtin_amdgcn_s_setprio(x)

// ===========================================================================
// gemm128: 128x256 tile, BK=64, 8 waves (2M x 4N), per-wave 64x64.
// TRIPLE buffer (3 x 48KB = 144KB): during tile t stage tile t+2
// (P0: A + B01 = 4 ops, P1: B23 = 2 ops). Single counted WAITVM(6) per
// K-tile at P1-end certifies tile t+1 (ops >=2.5 phases old); tile t+2's
// 6 ops stay in flight across the wait. 2 phases x 16 MFMA (grouped by kk).
// T2 swizzle byte^=((row&7)<<4) via pre-swizzled global source + read addr.
// Best-measured core in this session: 838 TF on proj (round 4).
// ===========================================================================
template<bool OUT_BF16>
__device__ __forceinline__ void gemm128(
    const short* __restrict__ Ab, int lda,
    const short* __restrict__ Bb, int ldb,
    void* __restrict__ Cb, int ldc,
    const float* __restrict__ bias, int K, float scale,
    int m0, int n0)
{
    constexpr int ABY  = 16384;
    constexpr int BUFB = ABY + 32768;  // 48KB
    __shared__ alignas(16) char smem[3 * BUFB];
    char* lds = smem;

    const int t    = threadIdx.x;
    const int lane = t & 63;
    const int wave = t >> 6;
    const int wr   = wave >> 2;
    const int wc   = wave & 3;
    const int lr   = lane & 15;
    const int lq   = lane >> 4;

    const int srow  = t >> 3;
    const int scol  = (((t & 7) * 16) ^ ((srow & 7) << 4)) >> 1;
    const short* pa0 = Ab + (size_t)(m0 + srow) * lda + scol;
    const short* pb0 = Bb + (size_t)(n0 + srow) * ldb + scol;
    const size_t rsa = (size_t)64 * lda;
    const size_t rsb = (size_t)64 * ldb;
    const int ldst = t * 16;

    const int roA = (wr * 64 + lr) * 128;
    const int roB = ABY + (wc * 64 + lr) * 128;
    const int cs  = (lane & 7) << 4;
    const int cp0 = (lq << 4) ^ cs;
    const int cp1 = (64 | (lq << 4)) ^ cs;

    floatx4 acc[4][4];
    #pragma unroll
    for (int m = 0; m < 4; ++m)
        #pragma unroll
        for (int n = 0; n < 4; ++n) acc[m][n] = (floatx4)(0.f);

    auto stA = [&](int d, int kt) { const short* p = pa0 + kt * 64;
        async16(p,       lds + d +        ldst);
        async16(p + rsa, lds + d + 8192 + ldst); };
    auto stB01 = [&](int d, int kt) { const short* p = pb0 + kt * 64;
        async16(p,       lds + d + ABY +        ldst);
        async16(p + rsb, lds + d + ABY + 8192 + ldst); };
    auto stB23 = [&](int d, int kt) { const short* p = pb0 + kt * 64;
        async16(p + 2 * rsb, lds + d + ABY + 16384 + ldst);
        async16(p + 3 * rsb, lds + d + ABY + 24576 + ldst); };

    const int NT = K >> 6;

    stA(0, 0); stB01(0, 0); stB23(0, 0);
    if (NT > 1) { stA(BUFB, 1); stB01(BUFB, 1); stB23(BUFB, 1); WAITVM(6); }
    else        { WAITVM(0); }
    BAR(); MEMFENCE;

    int cb = 0;
    for (int tt = 0; tt < NT; ++tt) {
        const char* rb = lds + cb;
        int sb = cb + 2 * BUFB; if (sb >= 3 * BUFB) sb -= 3 * BUFB;
        bf16x8 a[4], b[4];

        // P0 (k0); stage A + B01 of t+2
        #pragma unroll
        for (int m = 0; m < 4; ++m) a[m] = *(const bf16x8*)(rb + roA + m * 2048 + cp0);
        #pragma unroll
        for (int n = 0; n < 4; ++n) b[n] = *(const bf16x8*)(rb + roB + n * 2048 + cp0);
        if (tt + 2 < NT) { stA(sb, tt + 2); stB01(sb, tt + 2); }
        BAR(); MEMFENCE;
        PRIO(1);
        #pragma unroll
        for (int m = 0; m < 4; ++m)
            #pragma unroll
            for (int n = 0; n < 4; ++n)
                acc[m][n] = __builtin_amdgcn_mfma_f32_16x16x32_bf16(a[m], b[n], acc[m][n], 0, 0, 0);
        PRIO(0); MEMFENCE;
        BAR(); MEMFENCE;

        // P1 (k1); stage B23 of t+2; certify tile t+1
        #pragma unroll
        for (int m = 0; m < 4; ++m) a[m] = *(const bf16x8*)(rb + roA + m * 2048 + cp1);
        #pragma unroll
        for (int n = 0; n < 4; ++n) b[n] = *(const bf16x8*)(rb + roB + n * 2048 + cp1);
        if (tt + 2 < NT) stB23(sb, tt + 2);
        BAR(); MEMFENCE;
        PRIO(1);
        #pragma unroll
        for (int m = 0; m < 4; ++m)
            #pragma unroll
            for (int n = 0; n < 4; ++n)
                acc[m][n] = __builtin_amdgcn_mfma_f32_16x16x32_bf16(a[m], b[n], acc[m][n], 0, 0, 0);
        PRIO(0); MEMFENCE;
        if (tt + 1 < NT) {
            if (tt + 2 < NT) { WAITVM(6); } else { WAITVM(0); }
        }
        BAR(); MEMFENCE;
        cb += BUFB; if (cb >= 3 * BUFB) cb = 0;
    }

    #pragma unroll
    for (int n = 0; n < 4; ++n) {
        const int gn = n0 + wc * 64 + n * 16 + lr;
        const float bv = bias ? bias[gn] : 0.f;
        #pragma unroll
        for (int m = 0; m < 4; ++m) {
            #pragma unroll
            for (int r = 0; r < 4; ++r) {
                const int gm = m0 + wr * 64 + m * 16 + lq * 4 + r;
                const float v = acc[m][n][r] * scale + bv;
                if (OUT_BF16) ((short*)Cb)[(size_t)gm * ldc + gn] = f2bf(v);
                else          ((float*)Cb)[(size_t)gm * ldc + gn] = v;
            }
        }
    }
}

// ---------------------------------------------------------------------------
// proj: 768 blocks = 3 mats x 64 m-tiles(128) x 4 n-tiles(256), XCD-swizzled.
// (byte-identical to round-4 best: 61.5 us, 838 TF)
// ---------------------------------------------------------------------------
__global__ __launch_bounds__(512, 2)
void proj_qkv(const short* __restrict__ xq, const short* __restrict__ xk,
              const short* __restrict__ xv,
              const short* __restrict__ Wq_, const short* __restrict__ Wk_,
              const short* __restrict__ Wv_,
              const float* __restrict__ bq_, const float* __restrict__ bk_,
              const float* __restrict__ bv_,
              short* __restrict__ q, short* __restrict__ k, short* __restrict__ vp)
{
    const int b   = blockIdx.x;
    const int xcd = b & 7;
    const int i   = b >> 3;          // 0..95
    const int z   = i >> 5;          // 0..2 (q,k,v)
    const int r   = i & 31;
    const int mm  = r >> 2;          // 0..7
    const int nn  = r & 3;           // 0..3
    const short* X = (z == 0) ? xq : (z == 1) ? xk : xv;
    const short* W = (z == 0) ? Wq_ : (z == 1) ? Wk_ : Wv_;
    const float* bb = (z == 0) ? bq_ : (z == 1) ? bk_ : bv_;
    short* O = (z == 0) ? q : (z == 1) ? k : vp;
    gemm128<true>(X, DIMN, W, DIMN, (void*)O, DIMN, bb, DIMN, 1.f,
                  (xcd * 8 + mm) * 128, nn * 256);
}

// scores: 512 blocks = 4 batch x 16 m-tiles(128) x 8 n-tiles(256).
// Same core as proj/pv. batch = xcd>>1, m-half = xcd&1 (XCD-local panels).
__global__ __launch_bounds__(512, 2)
void gemm_scores(const short* __restrict__ q, const short* __restrict__ k,
                 short* __restrict__ S, float scale)
{
    const int b   = blockIdx.x;
    const int xcd = b & 7;
    const int i   = b >> 3;          // 0..63
    const int bz  = xcd >> 1;
    const int mh  = xcd & 1;
    const int mm  = i >> 3;          // 0..7
    const int nn  = i & 7;           // 0..7
    gemm128<true>(q + (size_t)bz * SEQ * DIMN, DIMN,
                  k + (size_t)bz * SEQ * DIMN, DIMN,
                  (void*)(S + (size_t)bz * SEQ * SEQ), SEQ,
                  nullptr, DIMN, scale,
                  (mh * 8 + mm) * 128, nn * 256);
}

// PV: 256 blocks, 128x256, K=2048 (unchanged round-4).
__global__ __launch_bounds__(512, 2)
void gemm_pv(const short* __restrict__ P, const short* __restrict__ vt,
             float* __restrict__ O)
{
    const int b   = blockIdx.x;
    const int xcd = b & 7;
    const int i   = b >> 3;          // 0..31
    const int bz  = xcd >> 1;
    const int mh  = xcd & 1;
    const int mm  = i >> 2;          // 0..7
    const int nn  = i & 3;           // 0..3
    gemm128<false>(P  + (size_t)bz * SEQ * SEQ,  SEQ,
                   vt + (size_t)bz * DIMN * SEQ, SEQ,
                   (void*)(O + (size_t)bz * SEQ * DIMN), DIMN,
                   nullptr, SEQ, 1.f,
                   (mh * 8 + mm) * 128, nn * 256);
}

// ---------------------------------------------------------------------------
// fp32 -> bf16 bulk convert, 6 arrays in one launch (z picks; z<3 weights).
// ---------------------------------------------------------------------------
__global__ __launch_bounds__(256)
void cvt6(const float* __restrict__ w0, short* __restrict__ ow0,
          const float* __restrict__ w1, short* __restrict__ ow1,
          const float* __restrict__ w2, short* __restrict__ ow2,
          const float* __restrict__ x0, short* __restrict__ ox0,
          const float* __restrict__ x1, short* __restrict__ ox1,
          const float* __restrict__ x2, short* __restrict__ ox2,
          int n8w, int n8x)
{
    const int z = blockIdx.z;
    const float* in; short* out; int n8;
    switch (z) {
        case 0: in = w0; out = ow0; n8 = n8w; break;
        case 1: in = w1; out = ow1; n8 = n8w; break;
        case 2: in = w2; out = ow2; n8 = n8w; break;
        case 3: in = x0; out = ox0; n8 = n8x; break;
        case 4: in = x1; out = ox1; n8 = n8x; break;
        default: in = x2; out = ox2; n8 = n8x; break;
    }
    const int i = blockIdx.x * 256 + threadIdx.x;
    if (i >= n8) return;
    const float4 a0 = ((const float4*)in)[(size_t)i * 2];
    const float4 a1 = ((const float4*)in)[(size_t)i * 2 + 1];
    const float v[8] = {a0.x, a0.y, a0.z, a0.w, a1.x, a1.y, a1.z, a1.w};
    bf16x8 o;
    #pragma unroll
    for (int j = 0; j < 8; ++j) o[j] = f2bf(v[j]);
    *(bf16x8*)(out + (size_t)i * 8) = o;
}

// ---------------------------------------------------------------------------
// Effective biases: out[n] = b[n] + dot(ctx, W[n,:]) (ctx only for q,k).
// ---------------------------------------------------------------------------
__global__ __launch_bounds__(256)
void bias3(const float* __restrict__ Wq, const float* __restrict__ Wk,
           const float* __restrict__ Wv,
           const float* __restrict__ bq, const float* __restrict__ bk,
           const float* __restrict__ bv,
           const float* __restrict__ ctx,
           float* __restrict__ oq, float* __restrict__ ok, float* __restrict__ ov)
{
    const int z = blockIdx.y;
    const float* W = (z == 0) ? Wq : (z == 1) ? Wk : Wv;
    const float* b = (z == 0) ? bq : (z == 1) ? bk : bv;
    float*       o = (z == 0) ? oq : (z == 1) ? ok : ov;
    const int n    = blockIdx.x * 4 + (threadIdx.x >> 6);
    const int lane = threadIdx.x & 63;
    float s = 0.f;
    if (z < 2) {
        const float* row = W + (size_t)n * DIMN;
        for (int k = lane * 4; k < DIMN; k += 256) {
            const float4 x = *(const float4*)(row + k);
            const float4 c = *(const float4*)(ctx + k);
            s += x.x * c.x + x.y * c.y + x.z * c.z + x.w * c.w;
        }
        #pragma unroll
        for (int off = 32; off > 0; off >>= 1) s += __shfl_xor(s, off);
    }
    if (lane == 0) o[n] = b[n] + s;
}

// ---------------------------------------------------------------------------
// bf16 transpose: in [B][S][D] -> out [B][D][S], 64x64 LDS tiles.
// ---------------------------------------------------------------------------
__global__ __launch_bounds__(256)
void transpose_v(const short* __restrict__ in, short* __restrict__ out)
{
    __shared__ short t[64][68];
    const int b  = blockIdx.z;
    const int d0 = blockIdx.x * 64;
    const int s0 = blockIdx.y * 64;
    const int r  = threadIdx.x >> 3;
    const int c  = (threadIdx.x & 7) * 8;
    #pragma unroll
    for (int h = 0; h < 2; ++h) {
        const int s = r + h * 32;
        bf16x8 v = *(const bf16x8*)(in + ((size_t)b * SEQ + s0 + s) * DIMN + d0 + c);
        #pragma unroll
        for (int j = 0; j < 8; ++j) t[c + j][s] = v[j];
    }
    __syncthreads();
    #pragma unroll
    for (int h = 0; h < 2; ++h) {
        const int d = r + h * 32;
        bf16x8 v;
        #pragma unroll
        for (int j = 0; j < 8; ++j) v[j] = t[d][c + j];
        *(bf16x8*)(out + ((size_t)b * DIMN + d0 + d) * SEQ + s0 + c) = v;
    }
}

// ---------------------------------------------------------------------------
// Row softmax, in place on bf16 [M1 rows][SEQ]. XCD-aligned with scores'
// writer (batch bz lives on XCDs {2bz, 2bz+1}) so reads hit that L2.
// ---------------------------------------------------------------------------
__global__ __launch_bounds__(256)
void softmax_kernel(short* __restrict__ P)
{
    const int bid = blockIdx.x;
    const int xcd = bid & 7;
    const int i   = bid >> 3;            // 0..1023
    const int row = (xcd >> 1) * SEQ + (xcd & 1) * 1024 + i;
    short* p = P + (size_t)row * SEQ;
    const int t    = threadIdx.x;
    const int lane = t & 63;
    const int wave = t >> 6;
    __shared__ float red[8];

    bf16x8 raw = *(const bf16x8*)(p + t * 8);
    float v[8];
    float mx = -1e30f;
    #pragma unroll
    for (int j = 0; j < 8; ++j) { v[j] = bf2f(raw[j]); mx = fmaxf(mx, v[j]); }
    #pragma unroll
    for (int off = 32; off > 0; off >>= 1) mx = fmaxf(mx, __shfl_xor(mx, off));
    if (lane == 0) red[wave] = mx;
    __syncthreads();
    mx = fmaxf(fmaxf(red[0], red[1]), fmaxf(red[2], red[3]));

    float e[8], s = 0.f;
    #pragma unroll
    for (int j = 0; j < 8; ++j) { e[j] = __expf(v[j] - mx); s += e[j]; }
    #pragma unroll
    for (int off = 32; off > 0; off >>= 1) s += __shfl_xor(s, off);
    if (lane == 0) red[4 + wave] = s;
    __syncthreads();
    s = red[4] + red[5] + red[6] + red[7];
    const float inv = 1.f / s;

    bf16x8 o;
    #pragma unroll
    for (int j = 0; j < 8; ++j) o[j] = f2bf(e[j] * inv);
    *(bf16x8*)(p + t * 8) = o;
}

// ---------------------------------------------------------------------------
extern "C" void kernel_launch(void* const* d_in, const int* in_sizes, int n_in,
                              void* d_out, int out_size, void* d_ws, size_t ws_size,
                              hipStream_t stream)
{
    const float* query = (const float*)d_in[0];
    const float* key_  = (const float*)d_in[1];
    const float* value = (const float*)d_in[2];
    const float* ctx   = (const float*)d_in[3];
    const float* Wq    = (const float*)d_in[4];
    const float* bq    = (const float*)d_in[5];
    const float* Wk    = (const float*)d_in[6];
    const float* bk    = (const float*)d_in[7];
    const float* Wv    = (const float*)d_in[8];
    const float* bv    = (const float*)d_in[9];

    // Workspace (80 MB) + d_out (32 MB) doubling as scratch for xv/vp:
    //   ws:  xq [0,16) xk [16,32)  -> dead after proj -> S_b [0,32)
    //        q_b [32,48) k_b [48,64)
    //        W3 [64,70) + biases    -> dead after proj -> v_t [64,80)
    //   d_out: xv [0,16) vp [16,32) -> dead after transpose -> final output
    char* ws = (char*)d_ws;
    char* od = (char*)d_out;
    const size_t MB = 1ull << 20;
    short* xq   = (short*)(ws);
    short* xk   = (short*)(ws + 16 * MB);
    short* q_b  = (short*)(ws + 32 * MB);
    short* k_b  = (short*)(ws + 48 * MB);
    short* Wq_b = (short*)(ws + 64 * MB);
    short* Wk_b = (short*)(ws + 66 * MB);
    short* Wv_b = (short*)(ws + 68 * MB);
    float* bq_e = (float*)(ws + 70 * MB);
    float* bk_e = (float*)(ws + 70 * MB + 4096);
    float* bv_e = (float*)(ws + 70 * MB + 8192);
    short* S_b  = (short*)(ws);
    short* v_t  = (short*)(ws + 64 * MB);
    short* xv   = (short*)(od);
    short* vp   = (short*)(od + 16 * MB);

    dim3 blk(256);
    dim3 blk512(512);
    const int W8 = DIMN * DIMN / 8;  // 131072
    const int X8 = M1 * DIMN / 8;    // 1048576

    cvt6<<<dim3(X8 / 256, 1, 6), blk, 0, stream>>>(Wq, Wq_b, Wk, Wk_b, Wv, Wv_b,
                                                   query, xq, key_, xk, value, xv,
                                                   W8, X8);
    bias3<<<dim3(DIMN / 4, 3), blk, 0, stream>>>(Wq, Wk, Wv, bq, bk, bv, ctx,
                                                 bq_e, bk_e, bv_e);

    proj_qkv<<<dim3(768), blk512, 0, stream>>>(xq, xk, xv, Wq_b, Wk_b, Wv_b,
                                               bq_e, bk_e, bv_e, q_b, k_b, vp);
    transpose_v<<<dim3(DIMN / 64, SEQ / 64, BATCH), blk, 0, stream>>>(vp, v_t);

    const float scale = 1.0f / 32.0f; // DIMN^-0.5
    gemm_scores<<<dim3(512), blk512, 0, stream>>>(q_b, k_b, S_b, scale);

    softmax_kernel<<<dim3(M1), blk, 0, stream>>>(S_b);

    gemm_pv<<<dim3(256), blk512, 0, stream>>>(S_b, v_t, (float*)d_out);
}